// Round 1
// baseline (261.619 us; speedup 1.0000x reference)
//
#include <hip/hip_runtime.h>
#include <hip/hip_bf16.h>
#include <cstdint>
#include <cstddef>

// Shapes (fixed): B=2, S=2048, E=1024, H=16, D=64
// qkv GEMM: M=4096, N=3072, K=1024 ; proj GEMM: M=4096, N=1024, K=1024
// RoPE angle depends only on (head, dim-pair) -> folded into W_attn/b_attn.

typedef float  f32x4 __attribute__((ext_vector_type(4)));
typedef __bf16 bf16x8 __attribute__((ext_vector_type(8)));

__device__ __forceinline__ unsigned short f2bf(float f) {
  union { __bf16 b; unsigned short u; } c; c.b = (__bf16)f; return c.u;
}
__device__ __forceinline__ unsigned short bf2u(__bf16 b) {
  union { __bf16 b; unsigned short u; } c; c.b = b; return c.u;
}

// ---------------- prep: cast hidden f32 -> bf16 ----------------
__global__ __launch_bounds__(256) void cast_x_k(const float* __restrict__ in,
                                                __bf16* __restrict__ out) {
  size_t i = (size_t)blockIdx.x * 256 + threadIdx.x;   // 524288 threads * 8 elems
  f32x4 a = *(const f32x4*)(in + i * 8);
  f32x4 b = *(const f32x4*)(in + i * 8 + 4);
  bf16x8 o;
  o[0]=(__bf16)a[0]; o[1]=(__bf16)a[1]; o[2]=(__bf16)a[2]; o[3]=(__bf16)a[3];
  o[4]=(__bf16)b[0]; o[5]=(__bf16)b[1]; o[6]=(__bf16)b[2]; o[7]=(__bf16)b[3];
  *(bf16x8*)(out + i * 8) = o;
}

// ------- prep: transpose W (K x N, f32) -> Wt (N x K, bf16), optional RoPE fold -------
template<bool ROPE>
__global__ __launch_bounds__(256) void transpose_rot_k(const float* __restrict__ W,
                                                       __bf16* __restrict__ Wt,
                                                       int Kd, int Nd) {
  __shared__ float tile[32][33];
  const int tx = threadIdx.x, ty = threadIdx.y;
  const int n0 = blockIdx.x * 32, k0 = blockIdx.y * 32;
#pragma unroll
  for (int i = 0; i < 4; i++)
    tile[ty + 8 * i][tx] = W[(size_t)(k0 + ty + 8 * i) * Nd + n0 + tx];
  __syncthreads();
#pragma unroll
  for (int i = 0; i < 4; i++) {
    int nl = ty + 8 * i;
    int n  = n0 + nl;
    float v;
    if (ROPE && n < 2048) {              // q and k regions get rotated
      int nn = n & 1023;
      int h = nn >> 6, d = nn & 63, ip = d >> 1;
      float ang = (float)h * powf(10000.0f, -(float)ip / 32.0f);
      float s, c; sincosf(ang, &s, &c);
      float xe = tile[tx][nl & ~1], xo = tile[tx][nl | 1];
      v = (d & 1) ? (xe * s + xo * c) : (xe * c - xo * s);
    } else {
      v = tile[tx][nl];
    }
    Wt[(size_t)n * Kd + k0 + tx] = (__bf16)v;
  }
}

// ---------------- prep: rotate b_attn ----------------
__global__ __launch_bounds__(256) void rot_bias_k(const float* __restrict__ b,
                                                  float* __restrict__ out) {
  int n = blockIdx.x * 256 + threadIdx.x;
  if (n < 3072) {
    float v;
    if (n < 2048) {
      int nn = n & 1023, h = nn >> 6, d = nn & 63, ip = d >> 1;
      float ang = (float)h * powf(10000.0f, -(float)ip / 32.0f);
      float s, c; sincosf(ang, &s, &c);
      float xe = b[n & ~1], xo = b[n | 1];
      v = (d & 1) ? (xe * s + xo * c) : (xe * c - xo * s);
    } else v = b[n];
    out[n] = v;
  }
}

// ---------------- GEMM: C = A(MxK) * Bt(NxK)^T + bias ----------------
// MODE 0: scatter bf16 into Q/K/V (B,H,S,D).  MODE 1: f32 row-major out.
template<int MODE>
__global__ __launch_bounds__(256) void gemm_bt_k(
    const __bf16* __restrict__ A, const __bf16* __restrict__ Bt,
    const float* __restrict__ bias, float* __restrict__ outf,
    __bf16* __restrict__ Qo, __bf16* __restrict__ Ko, __bf16* __restrict__ Vo,
    int M, int N, int K)
{
  __shared__ __align__(16) char Asm[8192];   // [128][32] bf16
  __shared__ __align__(16) char Bsm[8192];   // [128][32] bf16
  const int tid = threadIdx.x;
  const int m0 = blockIdx.y * 128, n0 = blockIdx.x * 128;
  const int wid = tid >> 6, lane = tid & 63;
  const int wr = wid >> 1, wc = wid & 1;
  const int li = lane & 15, gq = lane >> 4;

  const f32x4 fzero = {0.f, 0.f, 0.f, 0.f};
  f32x4 acc[4][4];
#pragma unroll
  for (int i = 0; i < 4; i++)
#pragma unroll
    for (int j = 0; j < 4; j++) acc[i][j] = fzero;

  const int NT = K >> 5;
  const int row0 = tid >> 2, cb = tid & 3;   // tile has 128 rows x 4 chunks of 16B
  const int row1 = row0 + 64;

  f32x4 pa0 = *(const f32x4*)(A  + (size_t)(m0 + row0) * K + cb * 8);
  f32x4 pa1 = *(const f32x4*)(A  + (size_t)(m0 + row1) * K + cb * 8);
  f32x4 pb0 = *(const f32x4*)(Bt + (size_t)(n0 + row0) * K + cb * 8);
  f32x4 pb1 = *(const f32x4*)(Bt + (size_t)(n0 + row1) * K + cb * 8);

  for (int kt = 0; kt < NT; ++kt) {
    __syncthreads();
    *(f32x4*)(Asm + row0 * 64 + cb * 16) = pa0;
    *(f32x4*)(Asm + row1 * 64 + cb * 16) = pa1;
    *(f32x4*)(Bsm + row0 * 64 + cb * 16) = pb0;
    *(f32x4*)(Bsm + row1 * 64 + cb * 16) = pb1;
    __syncthreads();
    if (kt + 1 < NT) {
      int ko = (kt + 1) * 32;
      pa0 = *(const f32x4*)(A  + (size_t)(m0 + row0) * K + ko + cb * 8);
      pa1 = *(const f32x4*)(A  + (size_t)(m0 + row1) * K + ko + cb * 8);
      pb0 = *(const f32x4*)(Bt + (size_t)(n0 + row0) * K + ko + cb * 8);
      pb1 = *(const f32x4*)(Bt + (size_t)(n0 + row1) * K + ko + cb * 8);
    }
    bf16x8 af[4], bfr[4];
#pragma unroll
    for (int mi = 0; mi < 4; mi++)
      af[mi] = *(const bf16x8*)(Asm + (wr * 64 + mi * 16 + li) * 64 + gq * 16);
#pragma unroll
    for (int ni = 0; ni < 4; ni++)
      bfr[ni] = *(const bf16x8*)(Bsm + (wc * 64 + ni * 16 + li) * 64 + gq * 16);
#pragma unroll
    for (int mi = 0; mi < 4; mi++)
#pragma unroll
      for (int ni = 0; ni < 4; ni++)
        acc[mi][ni] = __builtin_amdgcn_mfma_f32_16x16x32_bf16(af[mi], bfr[ni],
                                                              acc[mi][ni], 0, 0, 0);
  }

#pragma unroll
  for (int ni = 0; ni < 4; ni++) {
    const int n = n0 + wc * 64 + ni * 16 + li;
    const float bv = bias[n];
#pragma unroll
    for (int mi = 0; mi < 4; mi++) {
#pragma unroll
      for (int r = 0; r < 4; r++) {
        const int m = m0 + wr * 64 + mi * 16 + 4 * gq + r;
        const float val = acc[mi][ni][r] + bv;
        if (MODE == 0) {
          const int region = n >> 10, nn = n & 1023;
          const int h = nn >> 6, d = nn & 63;
          const int b = m >> 11, s = m & 2047;
          __bf16* dst = (region == 0) ? Qo : (region == 1) ? Ko : Vo;
          dst[(((size_t)(b * 16 + h)) * 2048 + s) * 64 + d] = (__bf16)val;
        } else {
          outf[(size_t)m * N + n] = val;
        }
      }
    }
  }
}

// ---------------- causal flash attention ----------------
// grid (qt=32, bh=32), 256 threads = 4 waves, 16 q-rows/wave, KT=64.
// Swapped QK^T: T = mfma(K_rows, Q_rows) -> lane holds T[j][i], i=lane&15 (q-row).
__global__ __launch_bounds__(256) void attn_k(
    const __bf16* __restrict__ Q, const __bf16* __restrict__ K,
    const __bf16* __restrict__ V, __bf16* __restrict__ O)
{
  __shared__ __align__(16) char Ksm[8192];      // [64][64] bf16, xor-swizzled
  __shared__ __align__(16) char Vsm[8192];      // Vt [d=64][k=64] bf16, xor-swizzled
  __shared__ __align__(16) char Psm[4][2048];   // per-wave P [16][64] bf16
  const int qt = blockIdx.x, bh = blockIdx.y;
  const int tid = threadIdx.x, wid = tid >> 6, lane = tid & 63;
  const int li = lane & 15, gq = lane >> 4;
  const size_t base = (size_t)bh * 2048 * 64;
  const int iq = qt * 64 + wid * 16 + li;
  const int swz = (li & 7) << 4;
  const f32x4 fzero = {0.f, 0.f, 0.f, 0.f};

  bf16x8 qf[2];
#pragma unroll
  for (int kc = 0; kc < 2; kc++)
    qf[kc] = *(const bf16x8*)(Q + base + (size_t)iq * 64 + kc * 32 + gq * 8);

  f32x4 o[4];
#pragma unroll
  for (int dn = 0; dn < 4; dn++) o[dn] = fzero;
  float mrun = -1e30f, lrun = 0.f;
  char* pw = Psm[wid];

  for (int kt = 0; kt <= qt; ++kt) {
    __syncthreads();
    // stage K tile [64 rows][64 d] bf16 (row-major, xor swizzle on 16B chunks)
#pragma unroll
    for (int c = 0; c < 2; c++) {
      int idx = tid + 256 * c;
      int row = idx >> 3, cbk = idx & 7;
      f32x4 dv = *(const f32x4*)(K + base + (size_t)(kt * 64 + row) * 64 + cbk * 8);
      *(f32x4*)(Ksm + ((row * 128 + cbk * 16) ^ ((row & 7) << 4))) = dv;
    }
    // stage V transposed: Vt[d][k] (pairs of k packed as b32 writes)
    {
      int kk = (tid >> 3) * 2;
      int d0 = (tid & 7) * 8;
      bf16x8 v0 = *(const bf16x8*)(V + base + (size_t)(kt * 64 + kk) * 64 + d0);
      bf16x8 v1 = *(const bf16x8*)(V + base + (size_t)(kt * 64 + kk + 1) * 64 + d0);
#pragma unroll
      for (int j = 0; j < 8; j++) {
        int d = d0 + j;
        unsigned w = (unsigned)bf2u(v0[j]) | ((unsigned)bf2u(v1[j]) << 16);
        *(unsigned*)(Vsm + ((d * 128 + kk * 2) ^ ((d & 7) << 4))) = w;
      }
    }
    __syncthreads();

    // ---- QK^T (swapped operands) ----
    f32x4 s4[4];
#pragma unroll
    for (int f = 0; f < 4; f++) s4[f] = fzero;
#pragma unroll
    for (int kc = 0; kc < 2; kc++) {
#pragma unroll
      for (int f = 0; f < 4; f++) {
        bf16x8 kf = *(const bf16x8*)(Ksm + (((f * 16 + li) * 128 + kc * 64 + gq * 16) ^ swz));
        s4[f] = __builtin_amdgcn_mfma_f32_16x16x32_bf16(kf, qf[kc], s4[f], 0, 0, 0);
      }
    }
    // ---- scale + causal mask + online softmax ----
    float p[4][4];
    float tmax = -1e30f;
#pragma unroll
    for (int f = 0; f < 4; f++)
#pragma unroll
      for (int r = 0; r < 4; r++) {
        float sv = s4[f][r] * 0.125f;
        int j = kt * 64 + f * 16 + 4 * gq + r;
        if (j > iq) sv = -1e30f;
        p[f][r] = sv;
        tmax = fmaxf(tmax, sv);
      }
    tmax = fmaxf(tmax, __shfl_xor(tmax, 16));
    tmax = fmaxf(tmax, __shfl_xor(tmax, 32));
    float mnew  = fmaxf(mrun, tmax);
    float alpha = __expf(mrun - mnew);
    mrun = mnew;
    float ts = 0.f;
#pragma unroll
    for (int f = 0; f < 4; f++)
#pragma unroll
      for (int r = 0; r < 4; r++) {
        float pv = __expf(p[f][r] - mnew);
        p[f][r] = pv;
        ts += pv;
      }
    ts += __shfl_xor(ts, 16);
    ts += __shfl_xor(ts, 32);
    lrun = lrun * alpha + ts;
#pragma unroll
    for (int r = 0; r < 4; r++) {
      float ar = __shfl(alpha, 4 * gq + r);
#pragma unroll
      for (int dn = 0; dn < 4; dn++) o[dn][r] *= ar;
    }
    // ---- P -> bf16 -> per-wave LDS (layout repack for PV A-operand) ----
#pragma unroll
    for (int f = 0; f < 4; f++) {
      unsigned lo = (unsigned)f2bf(p[f][0]) | ((unsigned)f2bf(p[f][1]) << 16);
      unsigned hi = (unsigned)f2bf(p[f][2]) | ((unsigned)f2bf(p[f][3]) << 16);
      uint2 w2; w2.x = lo; w2.y = hi;
      *(uint2*)(pw + ((li * 128 + f * 32 + gq * 8) ^ swz)) = w2;
    }
    // ---- PV ----
#pragma unroll
    for (int kc = 0; kc < 2; kc++) {
      bf16x8 paf = *(const bf16x8*)(pw + ((li * 128 + kc * 64 + gq * 16) ^ swz));
#pragma unroll
      for (int dn = 0; dn < 4; dn++) {
        bf16x8 vb = *(const bf16x8*)(Vsm + (((dn * 16 + li) * 128 + kc * 64 + gq * 16) ^ swz));
        o[dn] = __builtin_amdgcn_mfma_f32_16x16x32_bf16(paf, vb, o[dn], 0, 0, 0);
      }
    }
  }

  // ---- epilogue: normalize, write O as (B,S,E) bf16 ----
  const int b = bh >> 4, h = bh & 15;
#pragma unroll
  for (int r = 0; r < 4; r++) {
    float lr  = __shfl(lrun, 4 * gq + r);
    float inv = 1.0f / lr;
    int qrow = qt * 64 + wid * 16 + 4 * gq + r;
#pragma unroll
    for (int dn = 0; dn < 4; dn++) {
      O[((size_t)(b * 2048 + qrow)) * 1024 + h * 64 + dn * 16 + li] =
          (__bf16)(o[dn][r] * inv);
    }
  }
}

// ---------------- host launcher ----------------
extern "C" void kernel_launch(void* const* d_in, const int* in_sizes, int n_in,
                              void* d_out, int out_size, void* d_ws, size_t ws_size,
                              hipStream_t stream) {
  const float* hidden = (const float*)d_in[0];
  const float* W_attn = (const float*)d_in[1];
  const float* b_attn = (const float*)d_in[2];
  const float* W_proj = (const float*)d_in[3];
  const float* b_proj = (const float*)d_in[4];
  float* out = (float*)d_out;

  char* ws = (char*)d_ws;
  size_t off = 0;
  auto alloc = [&](size_t bytes) -> char* {
    char* p = ws + off;
    off += (bytes + 255) & ~(size_t)255;
    return p;
  };
  __bf16* Xb  = (__bf16*)alloc((size_t)4096 * 1024 * 2);   // hidden bf16
  __bf16* Wat = (__bf16*)alloc((size_t)3072 * 1024 * 2);   // rot(W_attn)^T bf16
  __bf16* Wpt = (__bf16*)alloc((size_t)1024 * 1024 * 2);   // W_proj^T bf16
  float*  ba  = (float*) alloc((size_t)3072 * 4);          // rot(b_attn)
  __bf16* Qb  = (__bf16*)alloc((size_t)32 * 2048 * 64 * 2);
  __bf16* Kb  = (__bf16*)alloc((size_t)32 * 2048 * 64 * 2);
  __bf16* Vb  = (__bf16*)alloc((size_t)32 * 2048 * 64 * 2);
  __bf16* Ob  = (__bf16*)alloc((size_t)4096 * 1024 * 2);   // attn out (B,S,E) bf16

  cast_x_k<<<2048, 256, 0, stream>>>(hidden, Xb);
  transpose_rot_k<true ><<<dim3(96, 32), dim3(32, 8), 0, stream>>>(W_attn, Wat, 1024, 3072);
  transpose_rot_k<false><<<dim3(32, 32), dim3(32, 8), 0, stream>>>(W_proj, Wpt, 1024, 1024);
  rot_bias_k<<<12, 256, 0, stream>>>(b_attn, ba);

  gemm_bt_k<0><<<dim3(24, 32), 256, 0, stream>>>(Xb, Wat, ba, nullptr,
                                                 Qb, Kb, Vb, 4096, 3072, 1024);
  attn_k<<<dim3(32, 32), 256, 0, stream>>>(Qb, Kb, Vb, Ob);
  gemm_bt_k<1><<<dim3(8, 32), 256, 0, stream>>>(Ob, Wpt, b_proj, out,
                                                nullptr, nullptr, nullptr,
                                                4096, 1024, 1024);
}

// Round 3
// 249.689 us; speedup vs baseline: 1.0478x; 1.0478x over previous
//
#include <hip/hip_runtime.h>
#include <hip/hip_bf16.h>
#include <cstdint>
#include <cstddef>

// Shapes (fixed): B=2, S=2048, E=1024, H=16, D=64
// qkv GEMM: M=4096, N=3072, K=1024 ; proj GEMM: M=4096, N=1024, K=1024
// RoPE angle depends only on (head, dim-pair) -> folded into W_attn/b_attn.

typedef float  f32x4 __attribute__((ext_vector_type(4)));
typedef __bf16 bf16x8 __attribute__((ext_vector_type(8)));

__device__ __forceinline__ unsigned short f2bf(float f) {
  union { __bf16 b; unsigned short u; } c; c.b = (__bf16)f; return c.u;
}
__device__ __forceinline__ unsigned short bf2u(__bf16 b) {
  union { __bf16 b; unsigned short u; } c; c.b = b; return c.u;
}

// async global->LDS, 16B per lane. lds base must be wave-uniform; HW writes
// base + lane*16. global src is per-lane.
__device__ __forceinline__ void gload_lds16(const void* g, void* l) {
  __builtin_amdgcn_global_load_lds(
      (const __attribute__((address_space(1))) unsigned int*)g,
      (__attribute__((address_space(3))) unsigned int*)l, 16, 0, 0);
}

// ---------------- prep: cast hidden f32 -> bf16 ----------------
__global__ __launch_bounds__(256) void cast_x_k(const float* __restrict__ in,
                                                __bf16* __restrict__ out) {
  size_t i = (size_t)blockIdx.x * 256 + threadIdx.x;
  f32x4 a = *(const f32x4*)(in + i * 8);
  f32x4 b = *(const f32x4*)(in + i * 8 + 4);
  bf16x8 o;
  o[0]=(__bf16)a[0]; o[1]=(__bf16)a[1]; o[2]=(__bf16)a[2]; o[3]=(__bf16)a[3];
  o[4]=(__bf16)b[0]; o[5]=(__bf16)b[1]; o[6]=(__bf16)b[2]; o[7]=(__bf16)b[3];
  *(bf16x8*)(out + i * 8) = o;
}

// ------- prep: transpose W (K x N, f32) -> Wt (N x K, bf16), optional RoPE fold -------
template<bool ROPE>
__global__ __launch_bounds__(256) void transpose_rot_k(const float* __restrict__ W,
                                                       __bf16* __restrict__ Wt,
                                                       int Kd, int Nd) {
  __shared__ float tile[32][33];
  const int tx = threadIdx.x, ty = threadIdx.y;
  const int n0 = blockIdx.x * 32, k0 = blockIdx.y * 32;
#pragma unroll
  for (int i = 0; i < 4; i++)
    tile[ty + 8 * i][tx] = W[(size_t)(k0 + ty + 8 * i) * Nd + n0 + tx];
  __syncthreads();
#pragma unroll
  for (int i = 0; i < 4; i++) {
    int nl = ty + 8 * i;
    int n  = n0 + nl;
    float v;
    if (ROPE && n < 2048) {              // q and k regions get rotated
      int nn = n & 1023;
      int h = nn >> 6, d = nn & 63, ip = d >> 1;
      float ang = (float)h * powf(10000.0f, -(float)ip / 32.0f);
      float s, c; sincosf(ang, &s, &c);
      float xe = tile[tx][nl & ~1], xo = tile[tx][nl | 1];
      v = (d & 1) ? (xe * s + xo * c) : (xe * c - xo * s);
    } else {
      v = tile[tx][nl];
    }
    Wt[(size_t)n * Kd + k0 + tx] = (__bf16)v;
  }
}

// ---------------- prep: rotate b_attn ----------------
__global__ __launch_bounds__(256) void rot_bias_k(const float* __restrict__ b,
                                                  float* __restrict__ out) {
  int n = blockIdx.x * 256 + threadIdx.x;
  if (n < 3072) {
    float v;
    if (n < 2048) {
      int nn = n & 1023, h = nn >> 6, d = nn & 63, ip = d >> 1;
      float ang = (float)h * powf(10000.0f, -(float)ip / 32.0f);
      float s, c; sincosf(ang, &s, &c);
      float xe = b[n & ~1], xo = b[n | 1];
      v = (d & 1) ? (xe * s + xo * c) : (xe * c - xo * s);
    } else v = b[n];
    out[n] = v;
  }
}

// ---------------- GEMM: C = A(MxK) * Bt(NxK)^T + bias ----------------
// m97 structure: global_load_lds width-16 staging, 128x128 tile, BK=32.
// MODE 0: scatter bf16 into Q/K/V (B,H,S,D).  MODE 1: f32 row-major out.
template<int MODE>
__global__ __launch_bounds__(256) void gemm_bt_k(
    const __bf16* __restrict__ A, const __bf16* __restrict__ Bt,
    const float* __restrict__ bias, float* __restrict__ outf,
    __bf16* __restrict__ Qo, __bf16* __restrict__ Ko, __bf16* __restrict__ Vo,
    int M, int N, int K)
{
  __shared__ __align__(16) char Asm[8192];   // [128][32] bf16 linear
  __shared__ __align__(16) char Bsm[8192];
  const int tid = threadIdx.x;
  const int m0 = blockIdx.y * 128, n0 = blockIdx.x * 128;
  const int wid = tid >> 6, lane = tid & 63;
  const int wr = wid >> 1, wc = wid & 1;
  const int li = lane & 15, gq = lane >> 4;

  const f32x4 fzero = {0.f, 0.f, 0.f, 0.f};
  f32x4 acc[4][4];
#pragma unroll
  for (int i = 0; i < 4; i++)
#pragma unroll
    for (int j = 0; j < 4; j++) acc[i][j] = fzero;

  const int NT = K >> 5;

  for (int kt = 0; kt < NT; ++kt) {
    const int ko = kt * 32;
    // issue async staging: 512 16B chunks per tile, 2 per thread per matrix
#pragma unroll
    for (int it = 0; it < 2; it++) {
      const int idx = wid * 128 + it * 64 + lane;   // 0..511
      const int row = idx >> 2, cb = idx & 3;
      char* la = Asm + (size_t)(wid * 128 + it * 64) * 16;  // wave-uniform base
      char* lb = Bsm + (size_t)(wid * 128 + it * 64) * 16;
      gload_lds16(A  + (size_t)(m0 + row) * K + ko + cb * 8, la);
      gload_lds16(Bt + (size_t)(n0 + row) * K + ko + cb * 8, lb);
    }
    __syncthreads();   // vmcnt(0) drain + barrier -> tile resident
    bf16x8 af[4], bfr[4];
#pragma unroll
    for (int mi = 0; mi < 4; mi++)
      af[mi] = *(const bf16x8*)(Asm + (wr * 64 + mi * 16 + li) * 64 + gq * 16);
#pragma unroll
    for (int ni = 0; ni < 4; ni++)
      bfr[ni] = *(const bf16x8*)(Bsm + (wc * 64 + ni * 16 + li) * 64 + gq * 16);
#pragma unroll
    for (int mi = 0; mi < 4; mi++)
#pragma unroll
      for (int ni = 0; ni < 4; ni++)
        acc[mi][ni] = __builtin_amdgcn_mfma_f32_16x16x32_bf16(af[mi], bfr[ni],
                                                              acc[mi][ni], 0, 0, 0);
    __syncthreads();   // reads done before next tile's staging
  }

#pragma unroll
  for (int ni = 0; ni < 4; ni++) {
    const int n = n0 + wc * 64 + ni * 16 + li;
    const float bv = bias[n];
#pragma unroll
    for (int mi = 0; mi < 4; mi++) {
#pragma unroll
      for (int r = 0; r < 4; r++) {
        const int m = m0 + wr * 64 + mi * 16 + 4 * gq + r;
        const float val = acc[mi][ni][r] + bv;
        if (MODE == 0) {
          const int region = n >> 10, nn = n & 1023;
          const int h = nn >> 6, d = nn & 63;
          const int b = m >> 11, s = m & 2047;
          __bf16* dst = (region == 0) ? Qo : (region == 1) ? Ko : Vo;
          dst[(((size_t)(b * 16 + h)) * 2048 + s) * 64 + d] = (__bf16)val;
        } else {
          outf[(size_t)m * N + n] = val;
        }
      }
    }
  }
}

// ---------------- causal flash attention ----------------
// grid (qt=16, bh=32), 512 threads = 8 waves, QBLK=128 (16 q-rows/wave), KT=64.
// Double-buffered K/V LDS; async-STAGE split: waves 0-3 stage K, 4-7 stage V^T.
// Swapped QK^T: s4 = mfma(K_rows, Q_cols) -> lane holds S^T[k][q=li].
__global__ __launch_bounds__(512) void attn_k(
    const __bf16* __restrict__ Q, const __bf16* __restrict__ K,
    const __bf16* __restrict__ V, __bf16* __restrict__ O)
{
  __shared__ __align__(16) char Ksm[2][8192];   // [64][64] bf16, xor-swizzled
  __shared__ __align__(16) char Vsm[2][8192];   // Vt [d=64][k=64] bf16, xor-swizzled
  __shared__ __align__(16) char Psm[8][2048];   // per-wave P [16][64] bf16
  const int qt = blockIdx.x, bh = blockIdx.y;
  const int tid = threadIdx.x, wid = tid >> 6, lane = tid & 63;
  const int li = lane & 15, gq = lane >> 4;
  const size_t base = (size_t)bh * 2048 * 64;
  const int iq = qt * 128 + wid * 16 + li;      // this lane's q-row (softmax dim)
  const int wkmax = qt * 128 + wid * 16 + 15;   // wave's max causal col
  const int swz = (li & 7) << 4;
  const f32x4 fzero = {0.f, 0.f, 0.f, 0.f};
  const int ktmax = 2 * qt + 1;

  bf16x8 qf[2];
#pragma unroll
  for (int kc = 0; kc < 2; kc++)
    qf[kc] = *(const bf16x8*)(Q + base + (size_t)iq * 64 + kc * 32 + gq * 8);

  f32x4 o[4];
#pragma unroll
  for (int dn = 0; dn < 4; dn++) o[dn] = fzero;
  float mrun = -1e30f, lrun = 0.f;
  char* pw = Psm[wid];

  // staging roles
  const bool roleK = (wid < 4);
  const int st = tid & 255;                  // index within role group
  const int krow0 = st >> 3, kcb = st & 7;   // K: 2 chunks (st, st+256)
  const int krow1 = krow0 + 32;
  const int vkk = (st >> 3) * 2, vd0 = (st & 7) * 8;   // V: rows vkk,vkk+1 x 8 d
  f32x4 kreg0, kreg1;
  bf16x8 vreg0, vreg1;

  auto loadTile = [&](int kt) {
    if (roleK) {
      kreg0 = *(const f32x4*)(K + base + (size_t)(kt * 64 + krow0) * 64 + kcb * 8);
      kreg1 = *(const f32x4*)(K + base + (size_t)(kt * 64 + krow1) * 64 + kcb * 8);
    } else {
      vreg0 = *(const bf16x8*)(V + base + (size_t)(kt * 64 + vkk)     * 64 + vd0);
      vreg1 = *(const bf16x8*)(V + base + (size_t)(kt * 64 + vkk + 1) * 64 + vd0);
    }
  };
  auto writeTile = [&](int buf) {
    if (roleK) {
      *(f32x4*)(Ksm[buf] + ((krow0 * 128 + kcb * 16) ^ ((krow0 & 7) << 4))) = kreg0;
      *(f32x4*)(Ksm[buf] + ((krow1 * 128 + kcb * 16) ^ ((krow1 & 7) << 4))) = kreg1;
    } else {
#pragma unroll
      for (int j = 0; j < 8; j++) {
        int d = vd0 + j;
        unsigned w = (unsigned)bf2u(vreg0[j]) | ((unsigned)bf2u(vreg1[j]) << 16);
        *(unsigned*)(Vsm[buf] + ((d * 128 + vkk * 2) ^ ((d & 7) << 4))) = w;
      }
    }
  };

  loadTile(0);
  writeTile(0);
  __syncthreads();
  int cur = 0;

  for (int kt = 0; kt <= ktmax; ++kt) {
    if (kt < ktmax) loadTile(kt + 1);        // issue early: hides under compute

    if (kt * 64 <= wkmax) {                  // wave-uniform causal skip
      // ---- QK^T (swapped operands) ----
      f32x4 s4[4];
#pragma unroll
      for (int f = 0; f < 4; f++) s4[f] = fzero;
#pragma unroll
      for (int kc = 0; kc < 2; kc++) {
#pragma unroll
        for (int f = 0; f < 4; f++) {
          bf16x8 kf = *(const bf16x8*)(Ksm[cur] +
              (((f * 16 + li) * 128 + kc * 64 + gq * 16) ^ swz));
          s4[f] = __builtin_amdgcn_mfma_f32_16x16x32_bf16(kf, qf[kc], s4[f], 0, 0, 0);
        }
      }
      // ---- scale + causal mask + online softmax ----
      float p[4][4];
      float tmax = -1e30f;
#pragma unroll
      for (int f = 0; f < 4; f++)
#pragma unroll
        for (int r = 0; r < 4; r++) {
          float sv = s4[f][r] * 0.125f;
          int j = kt * 64 + f * 16 + 4 * gq + r;
          if (j > iq) sv = -1e30f;
          p[f][r] = sv;
          tmax = fmaxf(tmax, sv);
        }
      tmax = fmaxf(tmax, __shfl_xor(tmax, 16));
      tmax = fmaxf(tmax, __shfl_xor(tmax, 32));
      float mnew  = fmaxf(mrun, tmax);
      float alpha = __expf(mrun - mnew);
      mrun = mnew;
      float ts = 0.f;
#pragma unroll
      for (int f = 0; f < 4; f++)
#pragma unroll
        for (int r = 0; r < 4; r++) {
          float pv = __expf(p[f][r] - mnew);
          p[f][r] = pv;
          ts += pv;
        }
      ts += __shfl_xor(ts, 16);
      ts += __shfl_xor(ts, 32);
      lrun = lrun * alpha + ts;
#pragma unroll
      for (int r = 0; r < 4; r++) {
        float ar = __shfl(alpha, 4 * gq + r);
#pragma unroll
        for (int dn = 0; dn < 4; dn++) o[dn][r] *= ar;
      }
      // ---- P -> bf16 -> per-wave LDS (repack for PV A-operand) ----
#pragma unroll
      for (int f = 0; f < 4; f++) {
        unsigned lo = (unsigned)f2bf(p[f][0]) | ((unsigned)f2bf(p[f][1]) << 16);
        unsigned hi = (unsigned)f2bf(p[f][2]) | ((unsigned)f2bf(p[f][3]) << 16);
        uint2 w2; w2.x = lo; w2.y = hi;
        *(uint2*)(pw + ((li * 128 + f * 32 + gq * 8) ^ swz)) = w2;
      }
      // ---- PV ----
#pragma unroll
      for (int kc = 0; kc < 2; kc++) {
        bf16x8 paf = *(const bf16x8*)(pw + ((li * 128 + kc * 64 + gq * 16) ^ swz));
#pragma unroll
        for (int dn = 0; dn < 4; dn++) {
          bf16x8 vb = *(const bf16x8*)(Vsm[cur] +
              (((dn * 16 + li) * 128 + kc * 64 + gq * 16) ^ swz));
          o[dn] = __builtin_amdgcn_mfma_f32_16x16x32_bf16(paf, vb, o[dn], 0, 0, 0);
        }
      }
    }

    if (kt < ktmax) {
      __syncthreads();          // all waves done reading buf cur^1 (and cur)
      writeTile(cur ^ 1);       // vmcnt waited here by compiler, not earlier
      __syncthreads();          // next tile resident
      cur ^= 1;
    }
  }

  // ---- epilogue: normalize, write O as (B,S,E) bf16 ----
  const int b = bh >> 4, h = bh & 15;
#pragma unroll
  for (int r = 0; r < 4; r++) {
    float lr  = __shfl(lrun, 4 * gq + r);
    float inv = 1.0f / lr;
    int qrow = qt * 128 + wid * 16 + 4 * gq + r;
#pragma unroll
    for (int dn = 0; dn < 4; dn++) {
      O[((size_t)(b * 2048 + qrow)) * 1024 + h * 64 + dn * 16 + li] =
          (__bf16)(o[dn][r] * inv);
    }
  }
}

// ---------------- host launcher ----------------
extern "C" void kernel_launch(void* const* d_in, const int* in_sizes, int n_in,
                              void* d_out, int out_size, void* d_ws, size_t ws_size,
                              hipStream_t stream) {
  const float* hidden = (const float*)d_in[0];
  const float* W_attn = (const float*)d_in[1];
  const float* b_attn = (const float*)d_in[2];
  const float* W_proj = (const float*)d_in[3];
  const float* b_proj = (const float*)d_in[4];
  float* out = (float*)d_out;

  char* ws = (char*)d_ws;
  size_t off = 0;
  auto alloc = [&](size_t bytes) -> char* {
    char* p = ws + off;
    off += (bytes + 255) & ~(size_t)255;
    return p;
  };
  __bf16* Xb  = (__bf16*)alloc((size_t)4096 * 1024 * 2);   // hidden bf16
  __bf16* Wat = (__bf16*)alloc((size_t)3072 * 1024 * 2);   // rot(W_attn)^T bf16
  __bf16* Wpt = (__bf16*)alloc((size_t)1024 * 1024 * 2);   // W_proj^T bf16
  float*  ba  = (float*) alloc((size_t)3072 * 4);          // rot(b_attn)
  __bf16* Qb  = (__bf16*)alloc((size_t)32 * 2048 * 64 * 2);
  __bf16* Kb  = (__bf16*)alloc((size_t)32 * 2048 * 64 * 2);
  __bf16* Vb  = (__bf16*)alloc((size_t)32 * 2048 * 64 * 2);
  __bf16* Ob  = (__bf16*)alloc((size_t)4096 * 1024 * 2);   // attn out (B,S,E) bf16

  cast_x_k<<<2048, 256, 0, stream>>>(hidden, Xb);
  transpose_rot_k<true ><<<dim3(96, 32), dim3(32, 8), 0, stream>>>(W_attn, Wat, 1024, 3072);
  transpose_rot_k<false><<<dim3(32, 32), dim3(32, 8), 0, stream>>>(W_proj, Wpt, 1024, 1024);
  rot_bias_k<<<12, 256, 0, stream>>>(b_attn, ba);

  gemm_bt_k<0><<<dim3(24, 32), 256, 0, stream>>>(Xb, Wat, ba, nullptr,
                                                 Qb, Kb, Vb, 4096, 3072, 1024);
  attn_k<<<dim3(16, 32), 512, 0, stream>>>(Qb, Kb, Vb, Ob);
  gemm_bt_k<1><<<dim3(8, 32), 256, 0, stream>>>(Ob, Wpt, b_proj, out,
                                                nullptr, nullptr, nullptr,
                                                4096, 1024, 1024);
}

// Round 11
// 219.758 us; speedup vs baseline: 1.1905x; 1.1362x over previous
//
#include <hip/hip_runtime.h>
#include <hip/hip_bf16.h>
#include <cstdint>
#include <cstddef>

// Shapes (fixed): B=2, S=2048, E=1024, H=16, D=64
// qkv GEMM: M=4096, N=3072, K=1024 ; proj GEMM: M=4096, N=1024, K=1024
// RoPE angle depends only on (head, dim-pair) -> folded into W_attn/b_attn.

typedef float  f32x4 __attribute__((ext_vector_type(4)));
typedef __bf16 bf16x8 __attribute__((ext_vector_type(8)));

__device__ __forceinline__ unsigned short f2bf(float f) {
  union { __bf16 b; unsigned short u; } c; c.b = (__bf16)f; return c.u;
}
__device__ __forceinline__ unsigned short bf2u(__bf16 b) {
  union { __bf16 b; unsigned short u; } c; c.b = b; return c.u;
}

// async global->LDS, 16B per lane. lds base must be wave-uniform; HW writes
// base + lane*16. global src is per-lane.
__device__ __forceinline__ void gload_lds16(const void* g, void* l) {
  __builtin_amdgcn_global_load_lds(
      (const __attribute__((address_space(1))) unsigned int*)g,
      (__attribute__((address_space(3))) unsigned int*)l, 16, 0, 0);
}

// ---------------- prep: cast hidden f32 -> bf16 ----------------
__global__ __launch_bounds__(256) void cast_x_k(const float* __restrict__ in,
                                                __bf16* __restrict__ out) {
  size_t i = (size_t)blockIdx.x * 256 + threadIdx.x;
  f32x4 a = *(const f32x4*)(in + i * 8);
  f32x4 b = *(const f32x4*)(in + i * 8 + 4);
  bf16x8 o;
  o[0]=(__bf16)a[0]; o[1]=(__bf16)a[1]; o[2]=(__bf16)a[2]; o[3]=(__bf16)a[3];
  o[4]=(__bf16)b[0]; o[5]=(__bf16)b[1]; o[6]=(__bf16)b[2]; o[7]=(__bf16)b[3];
  *(bf16x8*)(out + i * 8) = o;
}

// ------- prep: transpose W (K x N, f32) -> Wt (N x K, bf16), optional RoPE fold -------
template<bool ROPE>
__global__ __launch_bounds__(256) void transpose_rot_k(const float* __restrict__ W,
                                                       __bf16* __restrict__ Wt,
                                                       int Kd, int Nd) {
  __shared__ float tile[32][33];
  const int tx = threadIdx.x, ty = threadIdx.y;
  const int n0 = blockIdx.x * 32, k0 = blockIdx.y * 32;
#pragma unroll
  for (int i = 0; i < 4; i++)
    tile[ty + 8 * i][tx] = W[(size_t)(k0 + ty + 8 * i) * Nd + n0 + tx];
  __syncthreads();
#pragma unroll
  for (int i = 0; i < 4; i++) {
    int nl = ty + 8 * i;
    int n  = n0 + nl;
    float v;
    if (ROPE && n < 2048) {              // q and k regions get rotated
      int nn = n & 1023;
      int h = nn >> 6, d = nn & 63, ip = d >> 1;
      float ang = (float)h * powf(10000.0f, -(float)ip / 32.0f);
      float s, c; sincosf(ang, &s, &c);
      float xe = tile[tx][nl & ~1], xo = tile[tx][nl | 1];
      v = (d & 1) ? (xe * s + xo * c) : (xe * c - xo * s);
    } else {
      v = tile[tx][nl];
    }
    Wt[(size_t)n * Kd + k0 + tx] = (__bf16)v;
  }
}

// ---------------- prep: rotate b_attn ----------------
__global__ __launch_bounds__(256) void rot_bias_k(const float* __restrict__ b,
                                                  float* __restrict__ out) {
  int n = blockIdx.x * 256 + threadIdx.x;
  if (n < 3072) {
    float v;
    if (n < 2048) {
      int nn = n & 1023, h = nn >> 6, d = nn & 63, ip = d >> 1;
      float ang = (float)h * powf(10000.0f, -(float)ip / 32.0f);
      float s, c; sincosf(ang, &s, &c);
      float xe = b[n & ~1], xo = b[n | 1];
      v = (d & 1) ? (xe * s + xo * c) : (xe * c - xo * s);
    } else v = b[n];
    out[n] = v;
  }
}

// ---------------- GEMM: C = A(MxK) * Bt(NxK)^T + bias ----------------
// Double-buffered global_load_lds staging, ONE barrier per K-step:
//   stage(next -> buf^1) ; compute(buf) ; __syncthreads (vmcnt drain after compute)
// BM=128 fixed. BN=128: 4 waves as 2x2 (wave=64x64, acc 4x4).
//                BN=64 : 4 waves as 4x1 (wave=32x64, acc 2x4).
// MODE 0: scatter bf16 into Q/K/V (B,H,S,D).  MODE 1: f32 row-major out.
template<int MODE, int BN>
__global__ __launch_bounds__(256) void gemm_bt_k(
    const __bf16* __restrict__ A, const __bf16* __restrict__ Bt,
    const float* __restrict__ bias, float* __restrict__ outf,
    __bf16* __restrict__ Qo, __bf16* __restrict__ Ko, __bf16* __restrict__ Vo,
    int M, int N, int K)
{
  constexpr int MI = (BN == 128) ? 4 : 2;     // m-frags per wave
  __shared__ __align__(16) char Asm[2][8192];          // [128][32] bf16 linear
  __shared__ __align__(16) char Bsm[2][BN * 64];       // [BN][32] bf16 linear
  const int tid = threadIdx.x;
  const int m0 = blockIdx.y * 128, n0 = blockIdx.x * BN;
  const int wid = tid >> 6, lane = tid & 63;
  const int wr = (BN == 128) ? (wid >> 1) : wid;
  const int wc = (BN == 128) ? (wid & 1) : 0;
  const int li = lane & 15, gq = lane >> 4;

  const f32x4 fzero = {0.f, 0.f, 0.f, 0.f};
  f32x4 acc[MI][4];
#pragma unroll
  for (int i = 0; i < MI; i++)
#pragma unroll
    for (int j = 0; j < 4; j++) acc[i][j] = fzero;

  const int NT = K >> 5;

  auto stage = [&](int buf, int kt) {
    const int ko = kt * 32;
#pragma unroll
    for (int it = 0; it < 2; it++) {          // A: 512 chunks, 2/thread
      const int idx = wid * 128 + it * 64 + lane;
      const int row = idx >> 2, cb = idx & 3;
      gload_lds16(A + (size_t)(m0 + row) * K + ko + cb * 8,
                  Asm[buf] + (size_t)(wid * 128 + it * 64) * 16);
    }
    if constexpr (BN == 128) {
#pragma unroll
      for (int it = 0; it < 2; it++) {
        const int idx = wid * 128 + it * 64 + lane;
        const int row = idx >> 2, cb = idx & 3;
        gload_lds16(Bt + (size_t)(n0 + row) * K + ko + cb * 8,
                    Bsm[buf] + (size_t)(wid * 128 + it * 64) * 16);
      }
    } else {                                   // B: 256 chunks, 1/thread
      const int row = tid >> 2, cb = tid & 3;
      gload_lds16(Bt + (size_t)(n0 + row) * K + ko + cb * 8,
                  Bsm[buf] + (size_t)(wid * 64) * 16);
    }
  };

  stage(0, 0);
  __syncthreads();
  int cur = 0;

  for (int kt = 0; kt < NT; ++kt) {
    if (kt + 1 < NT) stage(cur ^ 1, kt + 1);   // in flight during compute
    bf16x8 af[MI], bfr[4];
#pragma unroll
    for (int mi = 0; mi < MI; mi++)
      af[mi] = *(const bf16x8*)(Asm[cur] + (wr * (MI * 16) + mi * 16 + li) * 64 + gq * 16);
#pragma unroll
    for (int ni = 0; ni < 4; ni++)
      bfr[ni] = *(const bf16x8*)(Bsm[cur] + (wc * 64 + ni * 16 + li) * 64 + gq * 16);
#pragma unroll
    for (int mi = 0; mi < MI; mi++)
#pragma unroll
      for (int ni = 0; ni < 4; ni++)
        acc[mi][ni] = __builtin_amdgcn_mfma_f32_16x16x32_bf16(af[mi], bfr[ni],
                                                              acc[mi][ni], 0, 0, 0);
    __syncthreads();   // drains staged loads (covered by compute) + read/write hazard
    cur ^= 1;
  }

#pragma unroll
  for (int ni = 0; ni < 4; ni++) {
    const int n = n0 + wc * 64 + ni * 16 + li;
    const float bv = bias[n];
#pragma unroll
    for (int mi = 0; mi < MI; mi++) {
#pragma unroll
      for (int r = 0; r < 4; r++) {
        const int m = m0 + wr * (MI * 16) + mi * 16 + 4 * gq + r;
        const float val = acc[mi][ni][r] + bv;
        if (MODE == 0) {
          const int region = n >> 10, nn = n & 1023;
          const int h = nn >> 6, d = nn & 63;
          const int b = m >> 11, s = m & 2047;
          __bf16* dst = (region == 0) ? Qo : (region == 1) ? Ko : Vo;
          dst[(((size_t)(b * 16 + h)) * 2048 + s) * 64 + d] = (__bf16)val;
        } else {
          outf[(size_t)m * N + n] = val;
        }
      }
    }
  }
}

// ---------------- causal flash attention ----------------
// grid (pair=16, bh=32), 256 threads = 4 waves, QBLK=64 (16 q-rows/wave), KT=64.
// Load balance: block p processes q-tiles qta=p and qtb=31-p -> 33 iters/block
// uniformly; 512 blocks = 2 independent blocks/CU for the whole kernel.
// Double-buffered K/V LDS, ONE barrier/iter; waves 0-1 stage K, 2-3 stage V^T.
// Swapped QK^T: s4 = mfma(K_rows, Q) -> lane holds S^T[k][q=li].
// Softmax in exp2 domain (scale = 0.125*log2e); mask only on diagonal tiles;
// defer-max (T13): skip O-rescale while tile max grows < 2^11.
__global__ __launch_bounds__(256) void attn_k(
    const __bf16* __restrict__ Q, const __bf16* __restrict__ K,
    const __bf16* __restrict__ V, __bf16* __restrict__ O)
{
  __shared__ __align__(16) char Ksm[2][8192];   // [64][64] bf16, xor-swizzled
  __shared__ __align__(16) char Vsm[2][8192];   // Vt [d=64][k=64] bf16, xor-swizzled
  __shared__ __align__(16) char Psm[4][2048];   // per-wave P [16][64] bf16
  const int pr = blockIdx.x, bh = blockIdx.y;
  const int qta = pr, qtb = 31 - pr;
  const int NTa = qta + 1;
  const int NT  = NTa + qtb + 1;                // == 33 always
  const int tid = threadIdx.x, wid = tid >> 6, lane = tid & 63;
  const int li = lane & 15, gq = lane >> 4;
  const size_t base = (size_t)bh * 2048 * 64;
  const int swz = (li & 7) << 4;
  const f32x4 fzero = {0.f, 0.f, 0.f, 0.f};
  const float SC = 0.18033688011f;              // 0.125 * log2(e)

  // Q fragments for both phases (loaded up front; +8 VGPR, avoids mid-loop vmcnt)
  const int rowa = qta * 64 + wid * 16 + li;
  const int rowb = qtb * 64 + wid * 16 + li;
  bf16x8 qfa[2], qfb[2], qcur[2];
#pragma unroll
  for (int kc = 0; kc < 2; kc++) {
    qfa[kc] = *(const bf16x8*)(Q + base + (size_t)rowa * 64 + kc * 32 + gq * 8);
    qfb[kc] = *(const bf16x8*)(Q + base + (size_t)rowb * 64 + kc * 32 + gq * 8);
  }
  qcur[0] = qfa[0]; qcur[1] = qfa[1];

  f32x4 o[4];
#pragma unroll
  for (int dn = 0; dn < 4; dn++) o[dn] = fzero;
  float mrun = -1e30f, lrun = 0.f;
  int iq = rowa;
  char* pw = Psm[wid];
  const int b = bh >> 4, h = bh & 15;

  auto epilogue = [&](int qt) {
#pragma unroll
    for (int r = 0; r < 4; r++) {
      float lr  = __shfl(lrun, 4 * gq + r);
      float inv = 1.0f / lr;
      int qrow = qt * 64 + wid * 16 + 4 * gq + r;
#pragma unroll
      for (int dn = 0; dn < 4; dn++) {
        O[((size_t)(b * 2048 + qrow)) * 1024 + h * 64 + dn * 16 + li] =
            (__bf16)(o[dn][r] * inv);
      }
    }
  };

  // ---- staging (roles: waves 0-1 K, waves 2-3 V-transpose) ----
  const bool roleK = (wid < 2);
  const int st = tid & 127;
  const int vkk = (st >> 3) * 4, vd0 = (st & 7) * 8;
  f32x4 kreg[4];
  bf16x8 vreg[4];

  auto loadTile = [&](int ko) {                 // ko = k row offset
    if (roleK) {
#pragma unroll
      for (int t = 0; t < 4; t++) {
        const int ci = st + 128 * t;
        const int row = ci >> 3, cb = ci & 7;
        kreg[t] = *(const f32x4*)(K + base + (size_t)(ko + row) * 64 + cb * 8);
      }
    } else {
#pragma unroll
      for (int u = 0; u < 4; u++)
        vreg[u] = *(const bf16x8*)(V + base + (size_t)(ko + vkk + u) * 64 + vd0);
    }
  };
  auto writeTile = [&](int buf) {
    if (roleK) {
#pragma unroll
      for (int t = 0; t < 4; t++) {
        const int ci = st + 128 * t;
        const int row = ci >> 3, cb = ci & 7;
        *(f32x4*)(Ksm[buf] + ((row * 128 + cb * 16) ^ ((row & 7) << 4))) = kreg[t];
      }
    } else {
#pragma unroll
      for (int j = 0; j < 8; j++) {
        const int d = vd0 + j;
        uint2 w;
        w.x = (unsigned)bf2u(vreg[0][j]) | ((unsigned)bf2u(vreg[1][j]) << 16);
        w.y = (unsigned)bf2u(vreg[2][j]) | ((unsigned)bf2u(vreg[3][j]) << 16);
        *(uint2*)(Vsm[buf] + ((d * 128 + vkk * 2) ^ ((d & 7) << 4))) = w;
      }
    }
  };

  auto kofs = [&](int i) { return (i < NTa ? i : i - NTa) * 64; };

  // ---- prologue ----
  loadTile(kofs(0));
  writeTile(0);
  loadTile(kofs(1));                            // NT >= 18 always
  __syncthreads();

  // ---- main loop: one barrier per iteration ----
  for (int i = 0; i < NT; ++i) {
    const int cur = i & 1;
    if (i + 1 < NT) writeTile(cur ^ 1);         // regs loaded ~1 iter ago
    if (i + 2 < NT) loadTile(kofs(i + 2));      // issue next loads

    if (i == NTa) {                             // phase a -> b transition
      epilogue(qta);
#pragma unroll
      for (int dn = 0; dn < 4; dn++) o[dn] = fzero;
      mrun = -1e30f; lrun = 0.f;
      iq = rowb;
      qcur[0] = qfb[0]; qcur[1] = qfb[1];
    }
    const bool diag = (i == NTa - 1) || (i == NT - 1);
    const int kbase = kofs(i);

    // ---- QK^T (swapped operands) ----
    f32x4 s4[4];
#pragma unroll
    for (int f = 0; f < 4; f++) s4[f] = fzero;
#pragma unroll
    for (int kc = 0; kc < 2; kc++) {
#pragma unroll
      for (int f = 0; f < 4; f++) {
        bf16x8 kf = *(const bf16x8*)(Ksm[cur] +
            (((f * 16 + li) * 128 + kc * 64 + gq * 16) ^ swz));
        s4[f] = __builtin_amdgcn_mfma_f32_16x16x32_bf16(kf, qcur[kc], s4[f], 0, 0, 0);
      }
    }
    // ---- scale (+ mask on diagonal tiles only), exp2 domain ----
    float p[4][4];
    float tmax = -1e30f;
    if (diag) {
#pragma unroll
      for (int f = 0; f < 4; f++)
#pragma unroll
        for (int r = 0; r < 4; r++) {
          float sv = s4[f][r] * SC;
          int j = kbase + f * 16 + 4 * gq + r;
          if (j > iq) sv = -1e30f;
          p[f][r] = sv;
          tmax = fmaxf(tmax, sv);
        }
    } else {
#pragma unroll
      for (int f = 0; f < 4; f++)
#pragma unroll
        for (int r = 0; r < 4; r++) {
          float sv = s4[f][r] * SC;
          p[f][r] = sv;
          tmax = fmaxf(tmax, sv);
        }
    }
    tmax = fmaxf(tmax, __shfl_xor(tmax, 16));
    tmax = fmaxf(tmax, __shfl_xor(tmax, 32));
    // ---- defer-max: rescale only when max grew past 2^11 headroom ----
    if (!__all(tmax - mrun <= 11.0f)) {
      float mnew  = fmaxf(mrun, tmax);
      float alpha = exp2f(mrun - mnew);
#pragma unroll
      for (int r = 0; r < 4; r++) {
        float ar = __shfl(alpha, 4 * gq + r);
#pragma unroll
        for (int dn = 0; dn < 4; dn++) o[dn][r] *= ar;
      }
      lrun *= alpha;
      mrun = mnew;
    }
    float ts = 0.f;
#pragma unroll
    for (int f = 0; f < 4; f++)
#pragma unroll
      for (int r = 0; r < 4; r++) {
        float pv = exp2f(p[f][r] - mrun);      // bounded by 2^11
        p[f][r] = pv;
        ts += pv;
      }
    ts += __shfl_xor(ts, 16);
    ts += __shfl_xor(ts, 32);
    lrun += ts;
    // ---- P -> bf16 -> per-wave LDS (repack for PV A-operand) ----
#pragma unroll
    for (int f = 0; f < 4; f++) {
      unsigned lo = (unsigned)f2bf(p[f][0]) | ((unsigned)f2bf(p[f][1]) << 16);
      unsigned hi = (unsigned)f2bf(p[f][2]) | ((unsigned)f2bf(p[f][3]) << 16);
      uint2 w2; w2.x = lo; w2.y = hi;
      *(uint2*)(pw + ((li * 128 + f * 32 + gq * 8) ^ swz)) = w2;
    }
    // ---- PV ----
#pragma unroll
    for (int kc = 0; kc < 2; kc++) {
      bf16x8 paf = *(const bf16x8*)(pw + ((li * 128 + kc * 64 + gq * 16) ^ swz));
#pragma unroll
      for (int dn = 0; dn < 4; dn++) {
        bf16x8 vb = *(const bf16x8*)(Vsm[cur] +
            (((dn * 16 + li) * 128 + kc * 64 + gq * 16) ^ swz));
        o[dn] = __builtin_amdgcn_mfma_f32_16x16x32_bf16(paf, vb, o[dn], 0, 0, 0);
      }
    }

    __syncthreads();   // single barrier: separates buf reads/writes across iters
  }

  epilogue(qtb);
}

// ---------------- host launcher ----------------
extern "C" void kernel_launch(void* const* d_in, const int* in_sizes, int n_in,
                              void* d_out, int out_size, void* d_ws, size_t ws_size,
                              hipStream_t stream) {
  const float* hidden = (const float*)d_in[0];
  const float* W_attn = (const float*)d_in[1];
  const float* b_attn = (const float*)d_in[2];
  const float* W_proj = (const float*)d_in[3];
  const float* b_proj = (const float*)d_in[4];
  float* out = (float*)d_out;

  char* ws = (char*)d_ws;
  size_t off = 0;
  auto alloc = [&](size_t bytes) -> char* {
    char* p = ws + off;
    off += (bytes + 255) & ~(size_t)255;
    return p;
  };
  __bf16* Xb  = (__bf16*)alloc((size_t)4096 * 1024 * 2);   // hidden bf16
  __bf16* Wat = (__bf16*)alloc((size_t)3072 * 1024 * 2);   // rot(W_attn)^T bf16
  __bf16* Wpt = (__bf16*)alloc((size_t)1024 * 1024 * 2);   // W_proj^T bf16
  float*  ba  = (float*) alloc((size_t)3072 * 4);          // rot(b_attn)
  __bf16* Qb  = (__bf16*)alloc((size_t)32 * 2048 * 64 * 2);
  __bf16* Kb  = (__bf16*)alloc((size_t)32 * 2048 * 64 * 2);
  __bf16* Vb  = (__bf16*)alloc((size_t)32 * 2048 * 64 * 2);
  __bf16* Ob  = (__bf16*)alloc((size_t)4096 * 1024 * 2);   // attn out (B,S,E) bf16

  cast_x_k<<<2048, 256, 0, stream>>>(hidden, Xb);
  transpose_rot_k<true ><<<dim3(96, 32), dim3(32, 8), 0, stream>>>(W_attn, Wat, 1024, 3072);
  transpose_rot_k<false><<<dim3(32, 32), dim3(32, 8), 0, stream>>>(W_proj, Wpt, 1024, 1024);
  rot_bias_k<<<12, 256, 0, stream>>>(b_attn, ba);

  gemm_bt_k<0, 128><<<dim3(24, 32), 256, 0, stream>>>(Xb, Wat, ba, nullptr,
                                                      Qb, Kb, Vb, 4096, 3072, 1024);
  attn_k<<<dim3(16, 32), 256, 0, stream>>>(Qb, Kb, Vb, Ob);
  gemm_bt_k<1, 64><<<dim3(16, 32), 256, 0, stream>>>(Ob, Wpt, b_proj, out,
                                                     nullptr, nullptr, nullptr,
                                                     4096, 1024, 1024);
}